// Round 1
// baseline (1138.264 us; speedup 1.0000x reference)
//
#include <hip/hip_runtime.h>
#include <hip/hip_bf16.h>

// Problem dims
constexpr int B   = 2;
constexpr int HH  = 7;    // history turns
constexpr int H   = 8;    // total turns
constexpr int L   = 256;
constexpr int C   = 512;
constexpr int NH  = 8;
constexpr int DH  = 64;
constexpr int KS  = 4;    // top-k slots
constexpr int BH  = B * H;          // 16
constexpr int M4  = B * H * L;      // 4096 rows
constexpr size_t S = (size_t)B * H * L * C;  // 2,097,152 elems

__device__ inline float bf2f(unsigned short u) {
    unsigned int x = ((unsigned int)u) << 16;
    return __uint_as_float(x);
}

// ---------------------------------------------------------------- concat ctx
__global__ __launch_bounds__(256) void concat_kernel(
    const float* __restrict__ hist, const float* __restrict__ cur,
    float* __restrict__ ctx)
{
    size_t i4 = (size_t)blockIdx.x * 256 + threadIdx.x;   // float4 index
    size_t elem = i4 * 4;
    int c  = (int)(elem & (C - 1));
    size_t rest = elem >> 9;                  // /C
    int l  = (int)(rest & (L - 1));
    int bh = (int)(rest >> 8);                // /L
    int h  = bh & (H - 1);
    int b  = bh >> 3;
    float4 v;
    if (h < HH) {
        size_t off = ((((size_t)b * HH + h) * L + l) * C + c);
        v = *reinterpret_cast<const float4*>(hist + off);
    } else {
        size_t off = (((size_t)b * L + l) * C + c);
        v = *reinterpret_cast<const float4*>(cur + off);
    }
    *reinterpret_cast<float4*>(ctx + elem) = v;
}

// ---------------------------------------------------------------- topk+softmax
__global__ void topk_kernel(const float* __restrict__ gmap,
                            float* __restrict__ attnw,
                            int* __restrict__ indxO,
                            int* __restrict__ expertO)
{
    int t = threadIdx.x;
    if (t >= BH) return;
    int h = t & (H - 1);
    const float* row = gmap + (size_t)t * H;
    float v[H];
    #pragma unroll
    for (int j = 0; j < H; ++j) v[j] = row[j];
    float sel[KS]; int si[KS];
    #pragma unroll
    for (int kk = 0; kk < KS; ++kk) {
        float best = -1e30f; int bi = 0;
        #pragma unroll
        for (int j = 0; j < H; ++j) {
            if (v[j] > best) { best = v[j]; bi = j; }
        }
        sel[kk] = best; si[kk] = bi; v[bi] = -1e30f;
    }
    float mx = sel[0];
    float w[KS]; float sum = 0.f;
    #pragma unroll
    for (int kk = 0; kk < KS; ++kk) { w[kk] = __expf(sel[kk] - mx); sum += w[kk]; }
    float inv = 1.f / sum;
    #pragma unroll
    for (int kk = 0; kk < KS; ++kk) {
        attnw[t * KS + kk] = w[kk] * inv;
        indxO[t * KS + kk] = si[kk];
        int e = (si[kk] == h) ? 0 : ((si[kk] > h) ? 2 : 1);
        expertO[t * KS + kk] = e;
    }
}

// ---------------------------------------------------------------- QKV proj GEMM
// Y[p] = X @ W[p] + b[p], p = expert*3 + {q,k,v}; X:(4096,512) f32; out bf16
__global__ __launch_bounds__(256) void proj_gemm(
    const float* __restrict__ X,
    const float* __restrict__ Wq, const float* __restrict__ Wk, const float* __restrict__ Wv,
    const float* __restrict__ bq, const float* __restrict__ bk, const float* __restrict__ bv,
    __hip_bfloat16* __restrict__ out)
{
    constexpr int BM = 128, BN = 128, BK = 16;
    int p = blockIdx.z;
    int e = p / 3, t = p % 3;
    const float* W    = (t == 0 ? Wq : (t == 1 ? Wk : Wv)) + (size_t)e * C * C;
    const float* bias = (t == 0 ? bq : (t == 1 ? bk : bv)) + (size_t)e * C;
    __hip_bfloat16* Y = out + (size_t)p * S;

    int m0 = blockIdx.y * BM;
    int n0 = blockIdx.x * BN;
    __shared__ float As[BK][BM + 1];
    __shared__ float Bs[BK][BN];
    int tid = threadIdx.x;
    int tr = tid / 16, tc = tid % 16;

    float acc[8][8] = {};
    for (int k0 = 0; k0 < C; k0 += BK) {
        // A tile (BM x BK) via float4, store transposed
        #pragma unroll
        for (int it = 0; it < 2; ++it) {
            int f4 = tid + 256 * it;
            int r  = f4 >> 2;
            int kc = (f4 & 3) << 2;
            float4 v = *reinterpret_cast<const float4*>(&X[(size_t)(m0 + r) * C + k0 + kc]);
            As[kc + 0][r] = v.x; As[kc + 1][r] = v.y;
            As[kc + 2][r] = v.z; As[kc + 3][r] = v.w;
        }
        // B tile (BK x BN) via float4
        #pragma unroll
        for (int it = 0; it < 2; ++it) {
            int f4 = tid + 256 * it;
            int r  = f4 >> 5;
            int cc = (f4 & 31) << 2;
            float4 v = *reinterpret_cast<const float4*>(&W[(size_t)(k0 + r) * C + n0 + cc]);
            *reinterpret_cast<float4*>(&Bs[r][cc]) = v;
        }
        __syncthreads();
        #pragma unroll
        for (int kk = 0; kk < BK; ++kk) {
            float a[8], bb[8];
            #pragma unroll
            for (int i = 0; i < 8; ++i) a[i] = As[kk][tr * 8 + i];
            #pragma unroll
            for (int j = 0; j < 8; ++j) bb[j] = Bs[kk][tc * 8 + j];
            #pragma unroll
            for (int i = 0; i < 8; ++i)
                #pragma unroll
                for (int j = 0; j < 8; ++j)
                    acc[i][j] += a[i] * bb[j];
        }
        __syncthreads();
    }
    #pragma unroll
    for (int i = 0; i < 8; ++i) {
        size_t m = m0 + tr * 8 + i;
        #pragma unroll
        for (int j = 0; j < 8; ++j) {
            int n = n0 + tc * 8 + j;
            Y[m * C + n] = __float2bfloat16(acc[i][j] + bias[n]);
        }
    }
}

// ---------------------------------------------------------------- attention
// one block per (head, slot, bh); 256 threads = query rows; online softmax
__global__ __launch_bounds__(256) void attn_kernel(
    const __hip_bfloat16* __restrict__ qkv,
    const int* __restrict__ indx, const int* __restrict__ expertArr,
    __hip_bfloat16* __restrict__ Obuf)
{
    int head = blockIdx.x;
    int slot = blockIdx.y;
    int bh   = blockIdx.z;
    int b    = bh / H;
    int mi   = bh * KS + slot;
    int src  = indx[mi];
    int e    = expertArr[mi];

    const unsigned short* qp = reinterpret_cast<const unsigned short*>(
        qkv + (size_t)(e * 3 + 0) * S + (size_t)bh * L * C + head * DH);
    const unsigned short* kp = reinterpret_cast<const unsigned short*>(
        qkv + (size_t)(e * 3 + 1) * S + (size_t)(b * H + src) * L * C + head * DH);
    const unsigned short* vp = reinterpret_cast<const unsigned short*>(
        qkv + (size_t)(e * 3 + 2) * S + (size_t)(b * H + src) * L * C + head * DH);

    __shared__ float Ks[128][DH];
    __shared__ float Vs[128][DH];

    int i = threadIdx.x;
    float q[DH];
    {
        const ushort4* q4 = reinterpret_cast<const ushort4*>(qp + (size_t)i * C);
        #pragma unroll
        for (int d4 = 0; d4 < DH / 4; ++d4) {
            ushort4 u = q4[d4];
            q[4 * d4 + 0] = bf2f(u.x); q[4 * d4 + 1] = bf2f(u.y);
            q[4 * d4 + 2] = bf2f(u.z); q[4 * d4 + 3] = bf2f(u.w);
        }
    }

    float m = -1e30f, lsum = 0.f;
    float O[DH];
    #pragma unroll
    for (int d = 0; d < DH; ++d) O[d] = 0.f;

    for (int c0 = 0; c0 < L; c0 += 128) {
        // cooperative load K,V chunk -> f32 LDS
        #pragma unroll
        for (int it = 0; it < 8; ++it) {
            int ch = threadIdx.x + 256 * it;    // ushort4 chunk id, 2048 total
            int elem = ch * 4;
            int r = elem >> 6;          // /DH
            int d = elem & (DH - 1);
            size_t goff = (size_t)(c0 + r) * C + d;
            ushort4 uk = *reinterpret_cast<const ushort4*>(kp + goff);
            Ks[r][d + 0] = bf2f(uk.x); Ks[r][d + 1] = bf2f(uk.y);
            Ks[r][d + 2] = bf2f(uk.z); Ks[r][d + 3] = bf2f(uk.w);
            ushort4 uv = *reinterpret_cast<const ushort4*>(vp + goff);
            Vs[r][d + 0] = bf2f(uv.x); Vs[r][d + 1] = bf2f(uv.y);
            Vs[r][d + 2] = bf2f(uv.z); Vs[r][d + 3] = bf2f(uv.w);
        }
        __syncthreads();
        for (int j = 0; j < 128; ++j) {
            float s = 0.f;
            #pragma unroll
            for (int d = 0; d < DH; ++d) s += q[d] * Ks[j][d];
            s *= 0.125f;
            if (s > m) {
                float sc = __expf(m - s);
                lsum *= sc;
                #pragma unroll
                for (int d = 0; d < DH; ++d) O[d] *= sc;
                m = s;
            }
            float w = __expf(s - m);
            lsum += w;
            #pragma unroll
            for (int d = 0; d < DH; ++d) O[d] += w * Vs[j][d];
        }
        __syncthreads();
    }
    float inv = 1.f / lsum;
    __hip_bfloat16* orow = Obuf + (size_t)mi * L * C + (size_t)i * C + head * DH;
    #pragma unroll
    for (int d = 0; d < DH; ++d) orow[d] = __float2bfloat16(O[d] * inv);
}

// ---------------------------------------------------------------- Wo + combine
// wise[bh] = sum_k a_k * (O_k @ Wo[e_k]) + sum_k a_k * bo[e_k]
__global__ __launch_bounds__(256) void wo_gemm(
    const __hip_bfloat16* __restrict__ Obuf,
    const float* __restrict__ Wo, const float* __restrict__ bo,
    const float* __restrict__ attnw, const int* __restrict__ expertArr,
    float* __restrict__ wise)
{
    constexpr int BM = 64, BN = 64, BK = 16;
    int bh = blockIdx.z;
    int m0 = blockIdx.y * BM;
    int n0 = blockIdx.x * BN;
    __shared__ float As[BK][BM + 1];
    __shared__ float Bs[BK][BN];
    int tid = threadIdx.x;
    int tr = tid / 16, tc = tid % 16;

    float Cacc[4][4] = {};
    float biasSum[4] = {};

    for (int k = 0; k < KS; ++k) {
        int mi = bh * KS + k;
        float a_k = attnw[mi];
        int e = expertArr[mi];
        const unsigned short* Ok = reinterpret_cast<const unsigned short*>(Obuf + (size_t)mi * L * C);
        const float* W = Wo + (size_t)e * C * C;
        float acc[4][4] = {};
        for (int k0 = 0; k0 < C; k0 += BK) {
            // A tile 64x16 bf16 -> f32 transposed; 256 ushort4 chunks, 1/thread
            {
                int r  = tid >> 2;
                int kc = (tid & 3) << 2;
                ushort4 u = *reinterpret_cast<const ushort4*>(&Ok[(size_t)(m0 + r) * C + k0 + kc]);
                As[kc + 0][r] = bf2f(u.x); As[kc + 1][r] = bf2f(u.y);
                As[kc + 2][r] = bf2f(u.z); As[kc + 3][r] = bf2f(u.w);
            }
            // B tile 16x64 f32: 256 float4 chunks, 1/thread
            {
                int r  = tid >> 4;
                int cc = (tid & 15) << 2;
                float4 v = *reinterpret_cast<const float4*>(&W[(size_t)(k0 + r) * C + n0 + cc]);
                *reinterpret_cast<float4*>(&Bs[r][cc]) = v;
            }
            __syncthreads();
            #pragma unroll
            for (int kk = 0; kk < BK; ++kk) {
                float a[4], bb[4];
                #pragma unroll
                for (int i = 0; i < 4; ++i) a[i] = As[kk][tr * 4 + i];
                #pragma unroll
                for (int j = 0; j < 4; ++j) bb[j] = Bs[kk][tc * 4 + j];
                #pragma unroll
                for (int i = 0; i < 4; ++i)
                    #pragma unroll
                    for (int j = 0; j < 4; ++j)
                        acc[i][j] += a[i] * bb[j];
            }
            __syncthreads();
        }
        #pragma unroll
        for (int i = 0; i < 4; ++i)
            #pragma unroll
            for (int j = 0; j < 4; ++j)
                Cacc[i][j] += a_k * acc[i][j];
        #pragma unroll
        for (int j = 0; j < 4; ++j)
            biasSum[j] += a_k * bo[(size_t)e * C + n0 + tc * 4 + j];
    }
    #pragma unroll
    for (int i = 0; i < 4; ++i) {
        size_t m = m0 + tr * 4 + i;
        #pragma unroll
        for (int j = 0; j < 4; ++j) {
            int n = n0 + tc * 4 + j;
            wise[(size_t)bh * L * C + m * C + n] = Cacc[i][j] + biasSum[j];
        }
    }
}

// ---------------------------------------------------------------- relu + add
__global__ __launch_bounds__(256) void ew_relu_add(
    const float* __restrict__ wise, const float* __restrict__ xin,
    float* __restrict__ xout)
{
    size_t i4 = (size_t)blockIdx.x * 256 + threadIdx.x;
    size_t elem = i4 * 4;
    float4 w = *reinterpret_cast<const float4*>(wise + elem);
    float4 x = *reinterpret_cast<const float4*>(xin + elem);
    float4 o;
    o.x = fmaxf(w.x, 0.f) + x.x;
    o.y = fmaxf(w.y, 0.f) + x.y;
    o.z = fmaxf(w.z, 0.f) + x.z;
    o.w = fmaxf(w.w, 0.f) + x.w;
    *reinterpret_cast<float4*>(xout + elem) = o;
}

// ----------------------------------------------------------------------------
extern "C" void kernel_launch(void* const* d_in, const int* in_sizes, int n_in,
                              void* d_out, int out_size, void* d_ws, size_t ws_size,
                              hipStream_t stream) {
    const float* gmap = (const float*)d_in[0];
    const float* hist = (const float*)d_in[1];
    const float* cur  = (const float*)d_in[2];
    const float* Wq   = (const float*)d_in[6];
    const float* bq   = (const float*)d_in[7];
    const float* Wk   = (const float*)d_in[8];
    const float* bk   = (const float*)d_in[9];
    const float* Wv   = (const float*)d_in[10];
    const float* bv   = (const float*)d_in[11];
    const float* Wo   = (const float*)d_in[12];
    const float* bo   = (const float*)d_in[13];
    float* outp       = (float*)d_out;

    char* ws = (char*)d_ws;
    float* ctx  = (float*)(ws);                    // 4S bytes
    float* x1   = (float*)(ws + 4 * S);            // 4S
    float* wise = (float*)(ws + 8 * S);            // 4S
    __hip_bfloat16* qkv  = (__hip_bfloat16*)(ws + 12 * S);           // 18S bytes
    __hip_bfloat16* Obuf = (__hip_bfloat16*)(ws + 30 * S);           // 8S bytes
    float* attnw  = (float*)(ws + 38 * S);         // 256 B
    int*   indx   = (int*)(ws + 38 * S + 256);     // 256 B
    int*   expert = (int*)(ws + 38 * S + 512);     // 256 B

    dim3 projGrid(C / 128, M4 / 128, 9);
    dim3 attnGrid(NH, KS, BH);
    dim3 woGrid(C / 64, L / 64, BH);
    int ewBlocks = (int)(S / 4 / 256);   // 2048

    concat_kernel<<<ewBlocks, 256, 0, stream>>>(hist, cur, ctx);
    topk_kernel<<<1, 64, 0, stream>>>(gmap, attnw, indx, expert);

    // ---- layer 1: x = ctx -> x1
    proj_gemm<<<projGrid, 256, 0, stream>>>(ctx, Wq, Wk, Wv, bq, bk, bv, qkv);
    attn_kernel<<<attnGrid, 256, 0, stream>>>(qkv, indx, expert, Obuf);
    wo_gemm<<<woGrid, 256, 0, stream>>>(Obuf, Wo, bo, attnw, expert, wise);
    ew_relu_add<<<ewBlocks, 256, 0, stream>>>(wise, ctx, x1);

    // ---- layer 2: x = x1 -> d_out
    proj_gemm<<<projGrid, 256, 0, stream>>>(x1, Wq, Wk, Wv, bq, bk, bv, qkv);
    attn_kernel<<<attnGrid, 256, 0, stream>>>(qkv, indx, expert, Obuf);
    wo_gemm<<<woGrid, 256, 0, stream>>>(Obuf, Wo, bo, attnw, expert, wise);
    ew_relu_add<<<ewBlocks, 256, 0, stream>>>(wise, x1, outp);
}

// Round 2
// 763.666 us; speedup vs baseline: 1.4905x; 1.4905x over previous
//
#include <hip/hip_runtime.h>
#include <hip/hip_bf16.h>

// Problem dims
constexpr int B   = 2;
constexpr int HH  = 7;    // history turns
constexpr int H   = 8;    // total turns
constexpr int L   = 256;
constexpr int C   = 512;
constexpr int NH  = 8;
constexpr int DH  = 64;
constexpr int KS  = 4;    // top-k slots
constexpr int BH  = B * H;          // 16
constexpr int M4  = B * H * L;      // 4096 rows
constexpr size_t S = (size_t)B * H * L * C;  // 2,097,152 elems

typedef __attribute__((ext_vector_type(8))) short short8;
typedef __attribute__((ext_vector_type(4))) float f32x4;
typedef unsigned short ushort_t;

__device__ inline float bf2f(unsigned short u) {
    unsigned int x = ((unsigned int)u) << 16;
    return __uint_as_float(x);
}
__device__ inline unsigned short f2bf(float f) {
    __hip_bfloat16 h = __float2bfloat16(f);
    return *reinterpret_cast<unsigned short*>(&h);
}
__device__ inline void gload16(const void* g, void* l) {
    __builtin_amdgcn_global_load_lds(
        (const __attribute__((address_space(1))) void*)g,
        (__attribute__((address_space(3))) void*)l,
        16, 0, 0);
}

// ---------------------------------------------------------------- concat ctx
__global__ __launch_bounds__(256) void concat_kernel(
    const float* __restrict__ hist, const float* __restrict__ cur,
    float* __restrict__ ctx)
{
    size_t i4 = (size_t)blockIdx.x * 256 + threadIdx.x;   // float4 index
    size_t elem = i4 * 4;
    int c  = (int)(elem & (C - 1));
    size_t rest = elem >> 9;                  // /C
    int l  = (int)(rest & (L - 1));
    int bh = (int)(rest >> 8);                // /L
    int h  = bh & (H - 1);
    int b  = bh >> 3;
    float4 v;
    if (h < HH) {
        size_t off = ((((size_t)b * HH + h) * L + l) * C + c);
        v = *reinterpret_cast<const float4*>(hist + off);
    } else {
        size_t off = (((size_t)b * L + l) * C + c);
        v = *reinterpret_cast<const float4*>(cur + off);
    }
    *reinterpret_cast<float4*>(ctx + elem) = v;
}

// ---------------------------------------------------------------- topk+softmax
__global__ void topk_kernel(const float* __restrict__ gmap,
                            float* __restrict__ attnw,
                            int* __restrict__ indxO,
                            int* __restrict__ expertO)
{
    int t = threadIdx.x;
    if (t >= BH) return;
    int h = t & (H - 1);
    const float* row = gmap + (size_t)t * H;
    float v[H];
    #pragma unroll
    for (int j = 0; j < H; ++j) v[j] = row[j];
    float sel[KS]; int si[KS];
    #pragma unroll
    for (int kk = 0; kk < KS; ++kk) {
        float best = -1e30f; int bi = 0;
        #pragma unroll
        for (int j = 0; j < H; ++j) {
            if (v[j] > best) { best = v[j]; bi = j; }
        }
        sel[kk] = best; si[kk] = bi; v[bi] = -1e30f;
    }
    float mx = sel[0];
    float w[KS]; float sum = 0.f;
    #pragma unroll
    for (int kk = 0; kk < KS; ++kk) { w[kk] = __expf(sel[kk] - mx); sum += w[kk]; }
    float inv = 1.f / sum;
    #pragma unroll
    for (int kk = 0; kk < KS; ++kk) {
        attnw[t * KS + kk] = w[kk] * inv;
        indxO[t * KS + kk] = si[kk];
        int e = (si[kk] == h) ? 0 : ((si[kk] > h) ? 2 : 1);
        expertO[t * KS + kk] = e;
    }
}

// ---------------------------------------------------------------- casts
// X (f32, row-major M4 x C) -> bf16 bits
__global__ __launch_bounds__(256) void cast_x_kernel(
    const float* __restrict__ X, ushort_t* __restrict__ Xb)
{
    size_t i = (size_t)blockIdx.x * 256 + threadIdx.x;
    float4 v = reinterpret_cast<const float4*>(X)[i];
    ushort4 o;
    o.x = f2bf(v.x); o.y = f2bf(v.y); o.z = f2bf(v.z); o.w = f2bf(v.w);
    reinterpret_cast<ushort4*>(Xb)[i] = o;
}

// W[p] (f32, [k][n]) -> Wt[p] (bf16 bits, [n][k])   p = e*3 + {q,k,v}
__global__ __launch_bounds__(256) void cast_w_kernel(
    const float* __restrict__ Wq, const float* __restrict__ Wk,
    const float* __restrict__ Wv, ushort_t* __restrict__ Wt)
{
    int p = blockIdx.z;
    int e = p / 3, t = p % 3;
    const float* W = (t == 0 ? Wq : (t == 1 ? Wk : Wv)) + (size_t)e * C * C;
    __shared__ float tile[32][33];
    int k0 = blockIdx.y * 32, n0 = blockIdx.x * 32;
    int tc = threadIdx.x & 31, tr = threadIdx.x >> 5;   // 8 rows / pass
    #pragma unroll
    for (int i = 0; i < 4; ++i) {
        int r = tr + i * 8;
        tile[r][tc] = W[(size_t)(k0 + r) * C + n0 + tc];
    }
    __syncthreads();
    #pragma unroll
    for (int i = 0; i < 4; ++i) {
        int r = tr + i * 8;   // row within n-tile
        Wt[(size_t)p * C * C + (size_t)(n0 + r) * C + k0 + tc] = f2bf(tile[tc][r]);
    }
}

// ---------------------------------------------------------------- QKV proj MFMA
// Y[p] = Xb @ W[p] + b[p];  Xb:(4096,512) bf16 [m][k]; Wt:(9,512,512) bf16 [n][k]
__global__ __launch_bounds__(256) void proj_mfma(
    const ushort_t* __restrict__ Xb, const ushort_t* __restrict__ Wt,
    const float* __restrict__ bq, const float* __restrict__ bk,
    const float* __restrict__ bv,
    ushort_t* __restrict__ out)
{
    constexpr int BK = 64;
    int p = blockIdx.z;
    int e = p / 3, t = p % 3;
    const float* bias = (t == 0 ? bq : (t == 1 ? bk : bv)) + (size_t)e * C;
    ushort_t* Y = out + (size_t)p * S;
    const ushort_t* Wp = Wt + (size_t)p * C * C;

    int m0 = blockIdx.y * 128;
    int n0 = blockIdx.x * 128;

    __shared__ ushort_t As[128 * BK];   // [row][k] 16 KB
    __shared__ ushort_t Bs[128 * BK];   // [col][k] 16 KB

    int tid  = threadIdx.x;
    int lane = tid & 63;
    int wid  = tid >> 6;
    int wr = wid >> 1, wc = wid & 1;

    f32x4 acc[4][4];
    #pragma unroll
    for (int m = 0; m < 4; ++m)
        #pragma unroll
        for (int n = 0; n < 4; ++n)
            acc[m][n] = (f32x4){0.f, 0.f, 0.f, 0.f};

    int rowA = wr * 64 + (lane & 15);
    int rowB = wc * 64 + (lane & 15);
    int kgrp = 8 * (lane >> 4);

    for (int kt = 0; kt < C / BK; ++kt) {
        int k0 = kt * BK;
        // stage A and B tiles: 4 x (A,B) global_load_lds dwordx4 per thread
        #pragma unroll
        for (int j = 0; j < 4; ++j) {
            int chunk = (wid * 4 + j) * 64 + lane;  // 16B chunk id, 0..1023
            int r = chunk >> 3;
            int k = (chunk & 7) << 3;
            gload16(Xb + (size_t)(m0 + r) * C + k0 + k, &As[(wid * 4 + j) * 512]);
            gload16(Wp + (size_t)(n0 + r) * C + k0 + k, &Bs[(wid * 4 + j) * 512]);
        }
        __syncthreads();
        #pragma unroll
        for (int ks = 0; ks < 2; ++ks) {
            int kb = ks * 32 + kgrp;
            short8 af[4], bfr[4];
            #pragma unroll
            for (int m = 0; m < 4; ++m)
                af[m] = *reinterpret_cast<const short8*>(&As[(rowA + m * 16) * BK + kb]);
            #pragma unroll
            for (int n = 0; n < 4; ++n)
                bfr[n] = *reinterpret_cast<const short8*>(&Bs[(rowB + n * 16) * BK + kb]);
            #pragma unroll
            for (int m = 0; m < 4; ++m)
                #pragma unroll
                for (int n = 0; n < 4; ++n)
                    acc[m][n] = __builtin_amdgcn_mfma_f32_16x16x32_bf16(
                        af[m], bfr[n], acc[m][n], 0, 0, 0);
        }
        __syncthreads();
    }

    // epilogue: D[row=(lane>>4)*4+r][col=lane&15] per 16x16 fragment
    int colb = n0 + wc * 64 + (lane & 15);
    int rowb = m0 + wr * 64 + (lane >> 4) * 4;
    #pragma unroll
    for (int n = 0; n < 4; ++n) {
        int col = colb + n * 16;
        float bcol = bias[col];
        #pragma unroll
        for (int m = 0; m < 4; ++m) {
            #pragma unroll
            for (int r = 0; r < 4; ++r) {
                int row = rowb + m * 16 + r;
                Y[(size_t)row * C + col] = f2bf(acc[m][n][r] + bcol);
            }
        }
    }
}

// ---------------------------------------------------------------- attention
// one block per (head, slot, bh); 256 threads = query rows; online softmax
__global__ __launch_bounds__(256) void attn_kernel(
    const __hip_bfloat16* __restrict__ qkv,
    const int* __restrict__ indx, const int* __restrict__ expertArr,
    __hip_bfloat16* __restrict__ Obuf)
{
    int head = blockIdx.x;
    int slot = blockIdx.y;
    int bh   = blockIdx.z;
    int b    = bh / H;
    int mi   = bh * KS + slot;
    int src  = indx[mi];
    int e    = expertArr[mi];

    const unsigned short* qp = reinterpret_cast<const unsigned short*>(
        qkv + (size_t)(e * 3 + 0) * S + (size_t)bh * L * C + head * DH);
    const unsigned short* kp = reinterpret_cast<const unsigned short*>(
        qkv + (size_t)(e * 3 + 1) * S + (size_t)(b * H + src) * L * C + head * DH);
    const unsigned short* vp = reinterpret_cast<const unsigned short*>(
        qkv + (size_t)(e * 3 + 2) * S + (size_t)(b * H + src) * L * C + head * DH);

    __shared__ float Ks[128][DH];
    __shared__ float Vs[128][DH];

    int i = threadIdx.x;
    float q[DH];
    {
        const ushort4* q4 = reinterpret_cast<const ushort4*>(qp + (size_t)i * C);
        #pragma unroll
        for (int d4 = 0; d4 < DH / 4; ++d4) {
            ushort4 u = q4[d4];
            q[4 * d4 + 0] = bf2f(u.x); q[4 * d4 + 1] = bf2f(u.y);
            q[4 * d4 + 2] = bf2f(u.z); q[4 * d4 + 3] = bf2f(u.w);
        }
    }

    float m = -1e30f, lsum = 0.f;
    float O[DH];
    #pragma unroll
    for (int d = 0; d < DH; ++d) O[d] = 0.f;

    for (int c0 = 0; c0 < L; c0 += 128) {
        #pragma unroll
        for (int it = 0; it < 8; ++it) {
            int ch = threadIdx.x + 256 * it;    // ushort4 chunk id, 2048 total
            int elem = ch * 4;
            int r = elem >> 6;          // /DH
            int d = elem & (DH - 1);
            size_t goff = (size_t)(c0 + r) * C + d;
            ushort4 uk = *reinterpret_cast<const ushort4*>(kp + goff);
            Ks[r][d + 0] = bf2f(uk.x); Ks[r][d + 1] = bf2f(uk.y);
            Ks[r][d + 2] = bf2f(uk.z); Ks[r][d + 3] = bf2f(uk.w);
            ushort4 uv = *reinterpret_cast<const ushort4*>(vp + goff);
            Vs[r][d + 0] = bf2f(uv.x); Vs[r][d + 1] = bf2f(uv.y);
            Vs[r][d + 2] = bf2f(uv.z); Vs[r][d + 3] = bf2f(uv.w);
        }
        __syncthreads();
        for (int j = 0; j < 128; ++j) {
            float s = 0.f;
            #pragma unroll
            for (int d = 0; d < DH; ++d) s += q[d] * Ks[j][d];
            s *= 0.125f;
            if (s > m) {
                float sc = __expf(m - s);
                lsum *= sc;
                #pragma unroll
                for (int d = 0; d < DH; ++d) O[d] *= sc;
                m = s;
            }
            float w = __expf(s - m);
            lsum += w;
            #pragma unroll
            for (int d = 0; d < DH; ++d) O[d] += w * Vs[j][d];
        }
        __syncthreads();
    }
    float inv = 1.f / lsum;
    __hip_bfloat16* orow = Obuf + (size_t)mi * L * C + (size_t)i * C + head * DH;
    #pragma unroll
    for (int d = 0; d < DH; ++d) orow[d] = __float2bfloat16(O[d] * inv);
}

// ---------------------------------------------------------------- Wo + combine
__global__ __launch_bounds__(256) void wo_gemm(
    const __hip_bfloat16* __restrict__ Obuf,
    const float* __restrict__ Wo, const float* __restrict__ bo,
    const float* __restrict__ attnw, const int* __restrict__ expertArr,
    float* __restrict__ wise)
{
    constexpr int BM = 64, BN = 64, BK = 16;
    int bh = blockIdx.z;
    int m0 = blockIdx.y * BM;
    int n0 = blockIdx.x * BN;
    __shared__ float As[BK][BM + 1];
    __shared__ float Bs[BK][BN];
    int tid = threadIdx.x;
    int tr = tid / 16, tc = tid % 16;

    float Cacc[4][4] = {};
    float biasSum[4] = {};

    for (int k = 0; k < KS; ++k) {
        int mi = bh * KS + k;
        float a_k = attnw[mi];
        int e = expertArr[mi];
        const unsigned short* Ok = reinterpret_cast<const unsigned short*>(Obuf + (size_t)mi * L * C);
        const float* W = Wo + (size_t)e * C * C;
        float acc[4][4] = {};
        for (int k0 = 0; k0 < C; k0 += BK) {
            {
                int r  = tid >> 2;
                int kc = (tid & 3) << 2;
                ushort4 u = *reinterpret_cast<const ushort4*>(&Ok[(size_t)(m0 + r) * C + k0 + kc]);
                As[kc + 0][r] = bf2f(u.x); As[kc + 1][r] = bf2f(u.y);
                As[kc + 2][r] = bf2f(u.z); As[kc + 3][r] = bf2f(u.w);
            }
            {
                int r  = tid >> 4;
                int cc = (tid & 15) << 2;
                float4 v = *reinterpret_cast<const float4*>(&W[(size_t)(k0 + r) * C + n0 + cc]);
                *reinterpret_cast<float4*>(&Bs[r][cc]) = v;
            }
            __syncthreads();
            #pragma unroll
            for (int kk = 0; kk < BK; ++kk) {
                float a[4], bb[4];
                #pragma unroll
                for (int i = 0; i < 4; ++i) a[i] = As[kk][tr * 4 + i];
                #pragma unroll
                for (int j = 0; j < 4; ++j) bb[j] = Bs[kk][tc * 4 + j];
                #pragma unroll
                for (int i = 0; i < 4; ++i)
                    #pragma unroll
                    for (int j = 0; j < 4; ++j)
                        acc[i][j] += a[i] * bb[j];
            }
            __syncthreads();
        }
        #pragma unroll
        for (int i = 0; i < 4; ++i)
            #pragma unroll
            for (int j = 0; j < 4; ++j)
                Cacc[i][j] += a_k * acc[i][j];
        #pragma unroll
        for (int j = 0; j < 4; ++j)
            biasSum[j] += a_k * bo[(size_t)e * C + n0 + tc * 4 + j];
    }
    #pragma unroll
    for (int i = 0; i < 4; ++i) {
        size_t m = m0 + tr * 4 + i;
        #pragma unroll
        for (int j = 0; j < 4; ++j) {
            int n = n0 + tc * 4 + j;
            wise[(size_t)bh * L * C + m * C + n] = Cacc[i][j] + biasSum[j];
        }
    }
}

// ---------------------------------------------------------------- relu + add
__global__ __launch_bounds__(256) void ew_relu_add(
    const float* __restrict__ wise, const float* __restrict__ xin,
    float* __restrict__ xout)
{
    size_t i4 = (size_t)blockIdx.x * 256 + threadIdx.x;
    size_t elem = i4 * 4;
    float4 w = *reinterpret_cast<const float4*>(wise + elem);
    float4 x = *reinterpret_cast<const float4*>(xin + elem);
    float4 o;
    o.x = fmaxf(w.x, 0.f) + x.x;
    o.y = fmaxf(w.y, 0.f) + x.y;
    o.z = fmaxf(w.z, 0.f) + x.z;
    o.w = fmaxf(w.w, 0.f) + x.w;
    *reinterpret_cast<float4*>(xout + elem) = o;
}

// ----------------------------------------------------------------------------
extern "C" void kernel_launch(void* const* d_in, const int* in_sizes, int n_in,
                              void* d_out, int out_size, void* d_ws, size_t ws_size,
                              hipStream_t stream) {
    const float* gmap = (const float*)d_in[0];
    const float* hist = (const float*)d_in[1];
    const float* cur  = (const float*)d_in[2];
    const float* Wq   = (const float*)d_in[6];
    const float* bq   = (const float*)d_in[7];
    const float* Wk   = (const float*)d_in[8];
    const float* bk   = (const float*)d_in[9];
    const float* Wv   = (const float*)d_in[10];
    const float* bv   = (const float*)d_in[11];
    const float* Wo   = (const float*)d_in[12];
    const float* bo   = (const float*)d_in[13];
    float* outp       = (float*)d_out;

    char* ws = (char*)d_ws;
    float* ctx  = (float*)(ws);                          // [0, 4S)
    float* x1   = (float*)(ws + 4 * S);                  // [4S, 8S)
    float* wise = (float*)(ws + 8 * S);                  // [8S, 12S)
    ushort_t* Xb = (ushort_t*)(ws + 8 * S);              // [8S, 10S)  shares w/ wise (disjoint in time)
    __hip_bfloat16* qkv  = (__hip_bfloat16*)(ws + 12 * S);   // [12S, 30S)
    __hip_bfloat16* Obuf = (__hip_bfloat16*)(ws + 30 * S);   // [30S, 38S)
    ushort_t* Wt = (ushort_t*)(ws + 30 * S);             // 9*C*C*2 = 4.7MB, shares w/ Obuf (re-cast per layer)
    float* attnw  = (float*)(ws + 38 * S);               // 256 B
    int*   indx   = (int*)(ws + 38 * S + 256);
    int*   expert = (int*)(ws + 38 * S + 512);

    dim3 projGrid(C / 128, M4 / 128, 9);
    dim3 castWGrid(C / 32, C / 32, 9);
    dim3 attnGrid(NH, KS, BH);
    dim3 woGrid(C / 64, L / 64, BH);
    int ewBlocks = (int)(S / 4 / 256);   // 2048

    concat_kernel<<<ewBlocks, 256, 0, stream>>>(hist, cur, ctx);
    topk_kernel<<<1, 64, 0, stream>>>(gmap, attnw, indx, expert);

    // ---- layer 1: x = ctx -> x1
    cast_w_kernel<<<castWGrid, 256, 0, stream>>>(Wq, Wk, Wv, Wt);
    cast_x_kernel<<<ewBlocks, 256, 0, stream>>>(ctx, Xb);
    proj_mfma<<<projGrid, 256, 0, stream>>>(Xb, Wt, bq, bk, bv, (ushort_t*)qkv);
    attn_kernel<<<attnGrid, 256, 0, stream>>>(qkv, indx, expert, Obuf);   // clobbers Wt
    wo_gemm<<<woGrid, 256, 0, stream>>>(Obuf, Wo, bo, attnw, expert, wise); // clobbers Xb
    ew_relu_add<<<ewBlocks, 256, 0, stream>>>(wise, ctx, x1);

    // ---- layer 2: x = x1 -> d_out
    cast_w_kernel<<<castWGrid, 256, 0, stream>>>(Wq, Wk, Wv, Wt);
    cast_x_kernel<<<ewBlocks, 256, 0, stream>>>(x1, Xb);
    proj_mfma<<<projGrid, 256, 0, stream>>>(Xb, Wt, bq, bk, bv, (ushort_t*)qkv);
    attn_kernel<<<attnGrid, 256, 0, stream>>>(qkv, indx, expert, Obuf);
    wo_gemm<<<woGrid, 256, 0, stream>>>(Obuf, Wo, bo, attnw, expert, wise);
    ew_relu_add<<<ewBlocks, 256, 0, stream>>>(wise, x1, outp);
}

// Round 3
// 276.804 us; speedup vs baseline: 4.1122x; 2.7589x over previous
//
#include <hip/hip_runtime.h>
#include <hip/hip_bf16.h>

// Problem dims
constexpr int B   = 2;
constexpr int HH  = 7;    // history turns
constexpr int H   = 8;    // total turns
constexpr int L   = 256;
constexpr int C   = 512;
constexpr int NH  = 8;
constexpr int DH  = 64;
constexpr int KS  = 4;    // top-k slots
constexpr int BH  = B * H;          // 16
constexpr int M4  = B * H * L;      // 4096 rows
constexpr size_t S = (size_t)B * H * L * C;  // 2,097,152 elems

typedef __attribute__((ext_vector_type(8))) short short8;
typedef __attribute__((ext_vector_type(4))) float f32x4;
typedef unsigned short u16;
typedef unsigned int u32;

__device__ inline float bf2f(u16 u) {
    u32 x = ((u32)u) << 16;
    return __uint_as_float(x);
}
__device__ inline u16 f2bf(float f) {
    __hip_bfloat16 h = __float2bfloat16(f);
    return *reinterpret_cast<u16*>(&h);
}
__device__ inline u32 packbf(float lo, float hi) {
    return ((u32)f2bf(hi) << 16) | (u32)f2bf(lo);
}
__device__ inline void gload16(const void* g, void* l) {
    __builtin_amdgcn_global_load_lds(
        (const __attribute__((address_space(1))) void*)g,
        (__attribute__((address_space(3))) void*)l,
        16, 0, 0);
}

// ---------------------------------------------------------------- concat ctx
__global__ __launch_bounds__(256) void concat_kernel(
    const float* __restrict__ hist, const float* __restrict__ cur,
    float* __restrict__ ctx)
{
    size_t i4 = (size_t)blockIdx.x * 256 + threadIdx.x;
    size_t elem = i4 * 4;
    int c  = (int)(elem & (C - 1));
    size_t rest = elem >> 9;
    int l  = (int)(rest & (L - 1));
    int bh = (int)(rest >> 8);
    int h  = bh & (H - 1);
    int b  = bh >> 3;
    float4 v;
    if (h < HH) {
        size_t off = ((((size_t)b * HH + h) * L + l) * C + c);
        v = *reinterpret_cast<const float4*>(hist + off);
    } else {
        size_t off = (((size_t)b * L + l) * C + c);
        v = *reinterpret_cast<const float4*>(cur + off);
    }
    *reinterpret_cast<float4*>(ctx + elem) = v;
}

// ---------------------------------------------------------------- topk+softmax
__global__ void topk_kernel(const float* __restrict__ gmap,
                            float* __restrict__ attnw,
                            int* __restrict__ indxO,
                            int* __restrict__ expertO)
{
    int t = threadIdx.x;
    if (t >= BH) return;
    int h = t & (H - 1);
    const float* row = gmap + (size_t)t * H;
    float v[H];
    #pragma unroll
    for (int j = 0; j < H; ++j) v[j] = row[j];
    float sel[KS]; int si[KS];
    #pragma unroll
    for (int kk = 0; kk < KS; ++kk) {
        float best = -1e30f; int bi = 0;
        #pragma unroll
        for (int j = 0; j < H; ++j) {
            if (v[j] > best) { best = v[j]; bi = j; }
        }
        sel[kk] = best; si[kk] = bi; v[bi] = -1e30f;
    }
    float mx = sel[0];
    float w[KS]; float sum = 0.f;
    #pragma unroll
    for (int kk = 0; kk < KS; ++kk) { w[kk] = __expf(sel[kk] - mx); sum += w[kk]; }
    float inv = 1.f / sum;
    #pragma unroll
    for (int kk = 0; kk < KS; ++kk) {
        attnw[t * KS + kk] = w[kk] * inv;
        indxO[t * KS + kk] = si[kk];
        int e = (si[kk] == h) ? 0 : ((si[kk] > h) ? 2 : 1);
        expertO[t * KS + kk] = e;
    }
}

// ---------------------------------------------------------------- casts
__global__ __launch_bounds__(256) void cast_x_kernel(
    const float* __restrict__ X, u16* __restrict__ Xb)
{
    size_t i = (size_t)blockIdx.x * 256 + threadIdx.x;
    float4 v = reinterpret_cast<const float4*>(X)[i];
    ushort4 o;
    o.x = f2bf(v.x); o.y = f2bf(v.y); o.z = f2bf(v.z); o.w = f2bf(v.w);
    reinterpret_cast<ushort4*>(Xb)[i] = o;
}

// W[p] (f32, [k][n]) -> Wt[p] (bf16, [n][k])   p = e*3 + {q,k,v}
__global__ __launch_bounds__(256) void cast_w_kernel(
    const float* __restrict__ Wq, const float* __restrict__ Wk,
    const float* __restrict__ Wv, u16* __restrict__ Wt)
{
    int p = blockIdx.z;
    int e = p / 3, t = p % 3;
    const float* W = (t == 0 ? Wq : (t == 1 ? Wk : Wv)) + (size_t)e * C * C;
    __shared__ float tile[32][33];
    int k0 = blockIdx.y * 32, n0 = blockIdx.x * 32;
    int tc = threadIdx.x & 31, tr = threadIdx.x >> 5;
    #pragma unroll
    for (int i = 0; i < 4; ++i) {
        int r = tr + i * 8;
        tile[r][tc] = W[(size_t)(k0 + r) * C + n0 + tc];
    }
    __syncthreads();
    #pragma unroll
    for (int i = 0; i < 4; ++i) {
        int r = tr + i * 8;
        Wt[(size_t)p * C * C + (size_t)(n0 + r) * C + k0 + tc] = f2bf(tile[tc][r]);
    }
}

// Wo[e] -> Wot[e] transposed bf16
__global__ __launch_bounds__(256) void cast_wo_kernel(
    const float* __restrict__ Wo, u16* __restrict__ Wot)
{
    int p = blockIdx.z;
    const float* W = Wo + (size_t)p * C * C;
    __shared__ float tile[32][33];
    int k0 = blockIdx.y * 32, n0 = blockIdx.x * 32;
    int tc = threadIdx.x & 31, tr = threadIdx.x >> 5;
    #pragma unroll
    for (int i = 0; i < 4; ++i) {
        int r = tr + i * 8;
        tile[r][tc] = W[(size_t)(k0 + r) * C + n0 + tc];
    }
    __syncthreads();
    #pragma unroll
    for (int i = 0; i < 4; ++i) {
        int r = tr + i * 8;
        Wot[(size_t)p * C * C + (size_t)(n0 + r) * C + k0 + tc] = f2bf(tile[tc][r]);
    }
}

// ---------------------------------------------------------------- QKV proj MFMA
__global__ __launch_bounds__(256) void proj_mfma(
    const u16* __restrict__ Xb, const u16* __restrict__ Wt,
    const float* __restrict__ bq, const float* __restrict__ bk,
    const float* __restrict__ bv,
    u16* __restrict__ out)
{
    constexpr int BK = 64;
    int p = blockIdx.z;
    int e = p / 3, t = p % 3;
    const float* bias = (t == 0 ? bq : (t == 1 ? bk : bv)) + (size_t)e * C;
    u16* Y = out + (size_t)p * S;
    const u16* Wp = Wt + (size_t)p * C * C;

    int m0 = blockIdx.y * 128;
    int n0 = blockIdx.x * 128;

    __shared__ u16 As[128 * BK];
    __shared__ u16 Bs[128 * BK];

    int tid  = threadIdx.x;
    int lane = tid & 63;
    int wid  = tid >> 6;
    int wr = wid >> 1, wc = wid & 1;

    f32x4 acc[4][4];
    #pragma unroll
    for (int m = 0; m < 4; ++m)
        #pragma unroll
        for (int n = 0; n < 4; ++n)
            acc[m][n] = (f32x4){0.f, 0.f, 0.f, 0.f};

    int rowA = wr * 64 + (lane & 15);
    int rowB = wc * 64 + (lane & 15);
    int kgrp = 8 * (lane >> 4);

    for (int kt = 0; kt < C / BK; ++kt) {
        int k0 = kt * BK;
        #pragma unroll
        for (int j = 0; j < 4; ++j) {
            int chunk = (wid * 4 + j) * 64 + lane;
            int r = chunk >> 3;
            int k = (chunk & 7) << 3;
            gload16(Xb + (size_t)(m0 + r) * C + k0 + k, &As[(wid * 4 + j) * 512]);
            gload16(Wp + (size_t)(n0 + r) * C + k0 + k, &Bs[(wid * 4 + j) * 512]);
        }
        __syncthreads();
        #pragma unroll
        for (int ks = 0; ks < 2; ++ks) {
            int kb = ks * 32 + kgrp;
            short8 af[4], bfr[4];
            #pragma unroll
            for (int m = 0; m < 4; ++m)
                af[m] = *reinterpret_cast<const short8*>(&As[(rowA + m * 16) * BK + kb]);
            #pragma unroll
            for (int n = 0; n < 4; ++n)
                bfr[n] = *reinterpret_cast<const short8*>(&Bs[(rowB + n * 16) * BK + kb]);
            #pragma unroll
            for (int m = 0; m < 4; ++m)
                #pragma unroll
                for (int n = 0; n < 4; ++n)
                    acc[m][n] = __builtin_amdgcn_mfma_f32_16x16x32_bf16(
                        af[m], bfr[n], acc[m][n], 0, 0, 0);
        }
        __syncthreads();
    }

    int colb = n0 + wc * 64 + (lane & 15);
    int rowb = m0 + wr * 64 + (lane >> 4) * 4;
    #pragma unroll
    for (int n = 0; n < 4; ++n) {
        int col = colb + n * 16;
        float bcol = bias[col];
        #pragma unroll
        for (int m = 0; m < 4; ++m) {
            #pragma unroll
            for (int r = 0; r < 4; ++r) {
                int row = rowb + m * 16 + r;
                Y[(size_t)row * C + col] = f2bf(acc[m][n][r] + bcol);
            }
        }
    }
}

// ---------------------------------------------------------------- MFMA flash attention
// block = (head, slot, bh); 4 waves; wave w owns q-columns [w*64, w*64+64)
// Swapped orientation: S^T = K Q^T, O^T = V^T P^T.
__global__ __launch_bounds__(256) void attn_mfma(
    const u16* __restrict__ qkv,
    const int* __restrict__ indx, const int* __restrict__ expertArr,
    u16* __restrict__ Obuf)
{
    int head = blockIdx.x;
    int slot = blockIdx.y;
    int bh   = blockIdx.z;
    int b    = bh >> 3;
    int mi   = bh * KS + slot;
    int src  = indx[mi];
    int e    = expertArr[mi];

    const u16* qp = qkv + (size_t)(e * 3 + 0) * S + (size_t)bh * L * C + head * DH;
    const u16* kp = qkv + (size_t)(e * 3 + 1) * S + (size_t)(b * H + src) * L * C + head * DH;
    const u16* vp = qkv + (size_t)(e * 3 + 2) * S + (size_t)(b * H + src) * L * C + head * DH;

    __shared__ u16 Ks[64 * 64];        // [kk][d] swizzled, 8KB
    __shared__ u16 Vt[64 * 64];        // [d][kk] swizzled, 8KB
    __shared__ u16 Pl[4][64 * 64];     // per-wave P[q][kk] swizzled, 32KB

    int tid = threadIdx.x, lane = tid & 63, w = tid >> 6;
    int c = lane & 15, gl = lane >> 4;

    // Q B-fragments: lane holds Q[q = w*64 + n*16 + c][d = kf*32 + 8gl + j]
    short8 qf[4][2];
    #pragma unroll
    for (int n = 0; n < 4; ++n)
        #pragma unroll
        for (int kf = 0; kf < 2; ++kf)
            qf[n][kf] = *reinterpret_cast<const short8*>(
                qp + (size_t)(w * 64 + n * 16 + c) * C + kf * 32 + 8 * gl);

    f32x4 accO[4][4];   // O^T[d = m'*16+4gl+r][q = n*16+c]
    #pragma unroll
    for (int m = 0; m < 4; ++m)
        #pragma unroll
        for (int n = 0; n < 4; ++n)
            accO[m][n] = (f32x4){0.f, 0.f, 0.f, 0.f};
    float mrun[4], lrun[4];
    #pragma unroll
    for (int n = 0; n < 4; ++n) { mrun[n] = -1e30f; lrun[n] = 0.f; }

    char* Plw = (char*)&Pl[w][0];

    for (int t = 0; t < 4; ++t) {
        int c0 = t * 64;
        __syncthreads();
        // --- stage K: [kk][d], XOR-swizzled rows (reg-staged)
        #pragma unroll
        for (int it = 0; it < 2; ++it) {
            int ch = tid + 256 * it;
            int r = ch >> 3, cb = ch & 7;
            short8 kv = *reinterpret_cast<const short8*>(kp + (size_t)(c0 + r) * C + cb * 8);
            int ad = (r * 128 + cb * 16) ^ ((r & 7) << 4);
            *reinterpret_cast<short8*>((char*)Ks + ad) = kv;
        }
        // --- stage V transposed: Vt[d][kk], pair-packed along kk
        {
            int rp = tid & 31;          // kk pair index
            int d0 = (tid >> 5) * 8;
            const u16* v0p = vp + (size_t)(c0 + 2 * rp) * C + d0;
            const u16* v1p = v0p + C;
            ushort4 a0 = *reinterpret_cast<const ushort4*>(v0p);
            ushort4 a1 = *reinterpret_cast<const ushort4*>(v0p + 4);
            ushort4 b0 = *reinterpret_cast<const ushort4*>(v1p);
            ushort4 b1 = *reinterpret_cast<const ushort4*>(v1p + 4);
            u16 va[8] = {a0.x, a0.y, a0.z, a0.w, a1.x, a1.y, a1.z, a1.w};
            u16 vb[8] = {b0.x, b0.y, b0.z, b0.w, b1.x, b1.y, b1.z, b1.w};
            #pragma unroll
            for (int j = 0; j < 8; ++j) {
                u32 pk = ((u32)vb[j] << 16) | (u32)va[j];
                int ad = ((d0 + j) * 128 + rp * 4) ^ (((d0 + j) & 7) << 4);
                *reinterpret_cast<u32*>((char*)Vt + ad) = pk;
            }
        }
        __syncthreads();

        // --- QK^T (swapped): accS = S^T tile [kk=64][q=64]
        f32x4 accS[4][4];
        #pragma unroll
        for (int m = 0; m < 4; ++m)
            #pragma unroll
            for (int n = 0; n < 4; ++n)
                accS[m][n] = (f32x4){0.f, 0.f, 0.f, 0.f};
        #pragma unroll
        for (int kf = 0; kf < 2; ++kf) {
            short8 ka[4];
            #pragma unroll
            for (int m = 0; m < 4; ++m) {
                int row = m * 16 + c;
                ka[m] = *reinterpret_cast<const short8*>(
                    (char*)Ks + ((row * 128 + (kf * 32 + 8 * gl) * 2) ^ ((row & 7) << 4)));
            }
            #pragma unroll
            for (int m = 0; m < 4; ++m)
                #pragma unroll
                for (int n = 0; n < 4; ++n)
                    accS[m][n] = __builtin_amdgcn_mfma_f32_16x16x32_bf16(
                        ka[m], qf[n][kf], accS[m][n], 0, 0, 0);
        }

        // --- online softmax per q-column (n); write P to wave-private LDS
        #pragma unroll
        for (int n = 0; n < 4; ++n) {
            float tm = -1e30f;
            #pragma unroll
            for (int m = 0; m < 4; ++m)
                #pragma unroll
                for (int r = 0; r < 4; ++r)
                    tm = fmaxf(tm, accS[m][n][r] * 0.125f);
            tm = fmaxf(tm, __shfl_xor(tm, 16));
            tm = fmaxf(tm, __shfl_xor(tm, 32));
            float nm = fmaxf(mrun[n], tm);
            float al = __expf(mrun[n] - nm);
            mrun[n] = nm;
            lrun[n] *= al;
            #pragma unroll
            for (int m = 0; m < 4; ++m)
                #pragma unroll
                for (int r = 0; r < 4; ++r)
                    accO[m][n][r] *= al;
            float ps = 0.f;
            #pragma unroll
            for (int m = 0; m < 4; ++m)
                #pragma unroll
                for (int r = 0; r < 4; ++r) {
                    float pv = __expf(accS[m][n][r] * 0.125f - nm);
                    accS[m][n][r] = pv;
                    ps += pv;
                }
            lrun[n] += ps;
            int row = n * 16 + c;
            int sw = (row & 7) << 4;
            #pragma unroll
            for (int m = 0; m < 4; ++m) {
                u32 p0 = packbf(accS[m][n][0], accS[m][n][1]);
                u32 p1 = packbf(accS[m][n][2], accS[m][n][3]);
                int base = row * 128 + (m * 16 + 4 * gl) * 2;
                *reinterpret_cast<u32*>(Plw + (base ^ sw)) = p0;
                *reinterpret_cast<u32*>(Plw + ((base + 4) ^ sw)) = p1;
            }
        }

        // --- PV (swapped): accO += V^T · P^T
        #pragma unroll
        for (int kf = 0; kf < 2; ++kf) {
            short8 va[4], pb[4];
            #pragma unroll
            for (int m = 0; m < 4; ++m) {
                int row = m * 16 + c;
                va[m] = *reinterpret_cast<const short8*>(
                    (char*)Vt + ((row * 128 + (kf * 32 + 8 * gl) * 2) ^ ((row & 7) << 4)));
            }
            #pragma unroll
            for (int n = 0; n < 4; ++n) {
                int row = n * 16 + c;
                pb[n] = *reinterpret_cast<const short8*>(
                    Plw + ((row * 128 + (kf * 32 + 8 * gl) * 2) ^ ((row & 7) << 4)));
            }
            #pragma unroll
            for (int m = 0; m < 4; ++m)
                #pragma unroll
                for (int n = 0; n < 4; ++n)
                    accO[m][n] = __builtin_amdgcn_mfma_f32_16x16x32_bf16(
                        va[m], pb[n], accO[m][n], 0, 0, 0);
        }
    }

    // --- epilogue: normalize, transpose via LDS, coalesced store
    float inv[4];
    #pragma unroll
    for (int n = 0; n < 4; ++n) {
        float lv = lrun[n];
        lv += __shfl_xor(lv, 16);
        lv += __shfl_xor(lv, 32);
        inv[n] = 1.f / lv;
    }
    #pragma unroll
    for (int m = 0; m < 4; ++m)
        #pragma unroll
        for (int n = 0; n < 4; ++n) {
            int row = n * 16 + c;          // q
            int sw = (row & 7) << 4;
            float o0 = accO[m][n][0] * inv[n];
            float o1 = accO[m][n][1] * inv[n];
            float o2 = accO[m][n][2] * inv[n];
            float o3 = accO[m][n][3] * inv[n];
            int base = row * 128 + (m * 16 + 4 * gl) * 2;   // d = m*16+4gl
            *reinterpret_cast<u32*>(Plw + (base ^ sw)) = packbf(o0, o1);
            *reinterpret_cast<u32*>(Plw + ((base + 4) ^ sw)) = packbf(o2, o3);
        }
    // wave-local readback (ds ordering within wave is compiler-enforced)
    #pragma unroll
    for (int it = 0; it < 8; ++it) {
        int q = it * 8 + (lane >> 3), cb = lane & 7;
        short8 ov = *reinterpret_cast<const short8*>(
            Plw + ((q * 128 + cb * 16) ^ ((q & 7) << 4)));
        *reinterpret_cast<short8*>(
            Obuf + ((size_t)mi * L + w * 64 + q) * C + head * DH + cb * 8) = ov;
    }
}

// ---------------------------------------------------------------- Wo + combine (MFMA)
// wise[bh] = sum_k a_k*(O_k @ Wo[e_k]) + sum_k a_k*bo[e_k]; a_k folded into A-staging
__global__ __launch_bounds__(256) void wo_mfma(
    const u16* __restrict__ Obuf, const u16* __restrict__ Wot,
    const float* __restrict__ bo,
    const float* __restrict__ attnw, const int* __restrict__ expertArr,
    float* __restrict__ wise)
{
    constexpr int BK = 64;
    int bh = blockIdx.z;
    int m0 = blockIdx.y * 64;
    int n0 = blockIdx.x * 128;

    __shared__ u16 As[64 * BK];    // 8KB, linear [row][k]
    __shared__ u16 Bs[128 * BK];   // 16KB

    int tid = threadIdx.x, lane = tid & 63, wid = tid >> 6;
    int wr = wid >> 1, wc = wid & 1;   // wave tile: rows wr*32+, cols wc*64+
    int c = lane & 15, gl = lane >> 4;

    f32x4 acc[2][4];
    #pragma unroll
    for (int m = 0; m < 2; ++m)
        #pragma unroll
        for (int n = 0; n < 4; ++n)
            acc[m][n] = (f32x4){0.f, 0.f, 0.f, 0.f};

    for (int k = 0; k < KS; ++k) {
        int mi = bh * KS + k;
        float ak = attnw[mi];
        int e = expertArr[mi];
        const u16* Ap = Obuf + (size_t)mi * L * C + (size_t)m0 * C;
        const u16* Bp = Wot + (size_t)e * C * C + (size_t)n0 * C;
        for (int kt = 0; kt < C / BK; ++kt) {
            int k0 = kt * BK;
            __syncthreads();
            // A: reg-stage 64x64 bf16, scaled by a_k
            #pragma unroll
            for (int it = 0; it < 2; ++it) {
                int ch = tid + 256 * it;
                int r = ch >> 3, cb = ch & 7;
                short8 a8 = *reinterpret_cast<const short8*>(Ap + (size_t)r * C + k0 + cb * 8);
                short8 o8;
                #pragma unroll
                for (int j = 0; j < 8; ++j)
                    o8[j] = (short)f2bf(bf2f((u16)a8[j]) * ak);
                *reinterpret_cast<short8*>(&As[r * BK + cb * 8]) = o8;
            }
            // B: async global->LDS
            #pragma unroll
            for (int j = 0; j < 4; ++j) {
                int chunk = (wid * 4 + j) * 64 + lane;
                int r = chunk >> 3;
                int kk = (chunk & 7) << 3;
                gload16(Bp + (size_t)r * C + k0 + kk, &Bs[(wid * 4 + j) * 512]);
            }
            __syncthreads();
            #pragma unroll
            for (int ks = 0; ks < 2; ++ks) {
                int kb = ks * 32 + 8 * gl;
                short8 af[2], bfr[4];
                #pragma unroll
                for (int m = 0; m < 2; ++m)
                    af[m] = *reinterpret_cast<const short8*>(&As[(wr * 32 + m * 16 + c) * BK + kb]);
                #pragma unroll
                for (int n = 0; n < 4; ++n)
                    bfr[n] = *reinterpret_cast<const short8*>(&Bs[(wc * 64 + n * 16 + c) * BK + kb]);
                #pragma unroll
                for (int m = 0; m < 2; ++m)
                    #pragma unroll
                    for (int n = 0; n < 4; ++n)
                        acc[m][n] = __builtin_amdgcn_mfma_f32_16x16x32_bf16(
                            af[m], bfr[n], acc[m][n], 0, 0, 0);
            }
        }
    }

    float biasS[4] = {0.f, 0.f, 0.f, 0.f};
    #pragma unroll
    for (int k = 0; k < KS; ++k) {
        int mi = bh * KS + k;
        float ak = attnw[mi];
        int e = expertArr[mi];
        #pragma unroll
        for (int n = 0; n < 4; ++n)
            biasS[n] += ak * bo[(size_t)e * C + n0 + wc * 64 + n * 16 + c];
    }
    #pragma unroll
    for (int m = 0; m < 2; ++m) {
        #pragma unroll
        for (int r = 0; r < 4; ++r) {
            int row = m0 + wr * 32 + m * 16 + 4 * gl + r;
            #pragma unroll
            for (int n = 0; n < 4; ++n) {
                int col = n0 + wc * 64 + n * 16 + c;
                wise[(size_t)bh * L * C + (size_t)row * C + col] = acc[m][n][r] + biasS[n];
            }
        }
    }
}

// ---------------------------------------------------------------- relu + add
__global__ __launch_bounds__(256) void ew_relu_add(
    const float* __restrict__ wise, const float* __restrict__ xin,
    float* __restrict__ xout)
{
    size_t i4 = (size_t)blockIdx.x * 256 + threadIdx.x;
    size_t elem = i4 * 4;
    float4 w = *reinterpret_cast<const float4*>(wise + elem);
    float4 x = *reinterpret_cast<const float4*>(xin + elem);
    float4 o;
    o.x = fmaxf(w.x, 0.f) + x.x;
    o.y = fmaxf(w.y, 0.f) + x.y;
    o.z = fmaxf(w.z, 0.f) + x.z;
    o.w = fmaxf(w.w, 0.f) + x.w;
    *reinterpret_cast<float4*>(xout + elem) = o;
}

// ----------------------------------------------------------------------------
extern "C" void kernel_launch(void* const* d_in, const int* in_sizes, int n_in,
                              void* d_out, int out_size, void* d_ws, size_t ws_size,
                              hipStream_t stream) {
    const float* gmap = (const float*)d_in[0];
    const float* hist = (const float*)d_in[1];
    const float* cur  = (const float*)d_in[2];
    const float* Wq   = (const float*)d_in[6];
    const float* bq   = (const float*)d_in[7];
    const float* Wk   = (const float*)d_in[8];
    const float* bk   = (const float*)d_in[9];
    const float* Wv   = (const float*)d_in[10];
    const float* bv   = (const float*)d_in[11];
    const float* Wo   = (const float*)d_in[12];
    const float* bo   = (const float*)d_in[13];
    float* outp       = (float*)d_out;

    char* ws = (char*)d_ws;
    float* ctx  = (float*)(ws);                      // [0,4S)
    float* x1   = (float*)(ws + 4 * S);              // [4S,8S)
    float* wise = (float*)(ws + 8 * S);              // [8S,12S)
    u16*   Xb   = (u16*)(ws + 8 * S);                // aliases wise (dead before wo writes)
    u16*   qkv  = (u16*)(ws + 12 * S);               // [12S,30S)
    u16*   Obuf = (u16*)(ws + 30 * S);               // [30S,38S)
    u16*   Wt   = (u16*)(ws + 30 * S);               // 9*C*C*2=4.7MB aliases Obuf; re-cast per layer
    float* attnw  = (float*)(ws + 38 * S);           // 256 B
    int*   indx   = (int*)(ws + 38 * S + 256);
    int*   expert = (int*)(ws + 38 * S + 512);
    u16*   Wot    = (u16*)(ws + 38 * S + 4096);      // 3*C*C*2 = 1.57MB

    dim3 projGrid(C / 128, M4 / 128, 9);
    dim3 castWGrid(C / 32, C / 32, 9);
    dim3 castWoGrid(C / 32, C / 32, 3);
    dim3 attnGrid(NH, KS, BH);
    dim3 woGrid(C / 128, L / 64, BH);
    int ewBlocks = (int)(S / 4 / 256);   // 2048

    concat_kernel<<<ewBlocks, 256, 0, stream>>>(hist, cur, ctx);
    topk_kernel<<<1, 64, 0, stream>>>(gmap, attnw, indx, expert);
    cast_wo_kernel<<<castWoGrid, 256, 0, stream>>>(Wo, Wot);

    // ---- layer 1: ctx -> x1
    cast_w_kernel<<<castWGrid, 256, 0, stream>>>(Wq, Wk, Wv, Wt);
    cast_x_kernel<<<ewBlocks, 256, 0, stream>>>(ctx, Xb);
    proj_mfma<<<projGrid, 256, 0, stream>>>(Xb, Wt, bq, bk, bv, qkv);
    attn_mfma<<<attnGrid, 256, 0, stream>>>(qkv, indx, expert, Obuf);  // clobbers Wt
    wo_mfma<<<woGrid, 256, 0, stream>>>(Obuf, Wot, bo, attnw, expert, wise);
    ew_relu_add<<<ewBlocks, 256, 0, stream>>>(wise, ctx, x1);

    // ---- layer 2: x1 -> out
    cast_w_kernel<<<castWGrid, 256, 0, stream>>>(Wq, Wk, Wv, Wt);
    cast_x_kernel<<<ewBlocks, 256, 0, stream>>>(x1, Xb);
    proj_mfma<<<projGrid, 256, 0, stream>>>(Xb, Wt, bq, bk, bv, qkv);
    attn_mfma<<<attnGrid, 256, 0, stream>>>(qkv, indx, expert, Obuf);
    wo_mfma<<<woGrid, 256, 0, stream>>>(Obuf, Wot, bo, attnw, expert, wise);
    ew_relu_add<<<ewBlocks, 256, 0, stream>>>(wise, x1, outp);
}

// Round 4
// 254.916 us; speedup vs baseline: 4.4653x; 1.0859x over previous
//
#include <hip/hip_runtime.h>
#include <hip/hip_bf16.h>

// Problem dims
constexpr int B   = 2;
constexpr int HH  = 7;    // history turns
constexpr int H   = 8;    // total turns
constexpr int L   = 256;
constexpr int C   = 512;
constexpr int NH  = 8;
constexpr int DH  = 64;
constexpr int KS  = 4;    // top-k slots
constexpr int BH  = B * H;          // 16
constexpr int M4  = B * H * L;      // 4096 rows
constexpr size_t S = (size_t)B * H * L * C;  // 2,097,152 elems

typedef __attribute__((ext_vector_type(8))) short short8;
typedef __attribute__((ext_vector_type(4))) float f32x4;
typedef unsigned short u16;
typedef unsigned int u32;

__device__ inline float bf2f(u16 u) {
    u32 x = ((u32)u) << 16;
    return __uint_as_float(x);
}
__device__ inline u16 f2bf(float f) {
    __hip_bfloat16 h = __float2bfloat16(f);
    return *reinterpret_cast<u16*>(&h);
}
__device__ inline u32 packbf(float lo, float hi) {
    return ((u32)f2bf(hi) << 16) | (u32)f2bf(lo);
}
__device__ inline void gload16(const void* g, void* l) {
    __builtin_amdgcn_global_load_lds(
        (const __attribute__((address_space(1))) void*)g,
        (__attribute__((address_space(3))) void*)l,
        16, 0, 0);
}

// ------------------------------------------------- concat ctx (+bf16 cast)
__global__ __launch_bounds__(256) void concat_cast_kernel(
    const float* __restrict__ hist, const float* __restrict__ cur,
    float* __restrict__ ctx, u16* __restrict__ Xb)
{
    size_t i4 = (size_t)blockIdx.x * 256 + threadIdx.x;
    size_t elem = i4 * 4;
    int c  = (int)(elem & (C - 1));
    size_t rest = elem >> 9;
    int l  = (int)(rest & (L - 1));
    int bh = (int)(rest >> 8);
    int h  = bh & (H - 1);
    int b  = bh >> 3;
    float4 v;
    if (h < HH) {
        size_t off = ((((size_t)b * HH + h) * L + l) * C + c);
        v = *reinterpret_cast<const float4*>(hist + off);
    } else {
        size_t off = (((size_t)b * L + l) * C + c);
        v = *reinterpret_cast<const float4*>(cur + off);
    }
    *reinterpret_cast<float4*>(ctx + elem) = v;
    ushort4 o;
    o.x = f2bf(v.x); o.y = f2bf(v.y); o.z = f2bf(v.z); o.w = f2bf(v.w);
    *reinterpret_cast<ushort4*>(Xb + elem) = o;
}

// ---------------------------------------------------------------- topk+softmax
__global__ void topk_kernel(const float* __restrict__ gmap,
                            float* __restrict__ attnw,
                            int* __restrict__ indxO,
                            int* __restrict__ expertO)
{
    int t = threadIdx.x;
    if (t >= BH) return;
    int h = t & (H - 1);
    const float* row = gmap + (size_t)t * H;
    float v[H];
    #pragma unroll
    for (int j = 0; j < H; ++j) v[j] = row[j];
    float sel[KS]; int si[KS];
    #pragma unroll
    for (int kk = 0; kk < KS; ++kk) {
        float best = -1e30f; int bi = 0;
        #pragma unroll
        for (int j = 0; j < H; ++j) {
            if (v[j] > best) { best = v[j]; bi = j; }
        }
        sel[kk] = best; si[kk] = bi; v[bi] = -1e30f;
    }
    float mx = sel[0];
    float w[KS]; float sum = 0.f;
    #pragma unroll
    for (int kk = 0; kk < KS; ++kk) { w[kk] = __expf(sel[kk] - mx); sum += w[kk]; }
    float inv = 1.f / sum;
    #pragma unroll
    for (int kk = 0; kk < KS; ++kk) {
        attnw[t * KS + kk] = w[kk] * inv;
        indxO[t * KS + kk] = si[kk];
        int e = (si[kk] == h) ? 0 : ((si[kk] > h) ? 2 : 1);
        expertO[t * KS + kk] = e;
    }
}

// ---------------------------------------------------------------- weight casts
// W[p] (f32, [k][n]) -> Wt[p] (bf16, [n][k])   p = e*3 + {q,k,v}
__global__ __launch_bounds__(256) void cast_w_kernel(
    const float* __restrict__ Wq, const float* __restrict__ Wk,
    const float* __restrict__ Wv, u16* __restrict__ Wt)
{
    int p = blockIdx.z;
    int e = p / 3, t = p % 3;
    const float* W = (t == 0 ? Wq : (t == 1 ? Wk : Wv)) + (size_t)e * C * C;
    __shared__ float tile[32][33];
    int k0 = blockIdx.y * 32, n0 = blockIdx.x * 32;
    int tc = threadIdx.x & 31, tr = threadIdx.x >> 5;
    #pragma unroll
    for (int i = 0; i < 4; ++i) {
        int r = tr + i * 8;
        tile[r][tc] = W[(size_t)(k0 + r) * C + n0 + tc];
    }
    __syncthreads();
    #pragma unroll
    for (int i = 0; i < 4; ++i) {
        int r = tr + i * 8;
        Wt[(size_t)p * C * C + (size_t)(n0 + r) * C + k0 + tc] = f2bf(tile[tc][r]);
    }
}

__global__ __launch_bounds__(256) void cast_wo_kernel(
    const float* __restrict__ Wo, u16* __restrict__ Wot)
{
    int p = blockIdx.z;
    const float* W = Wo + (size_t)p * C * C;
    __shared__ float tile[32][33];
    int k0 = blockIdx.y * 32, n0 = blockIdx.x * 32;
    int tc = threadIdx.x & 31, tr = threadIdx.x >> 5;
    #pragma unroll
    for (int i = 0; i < 4; ++i) {
        int r = tr + i * 8;
        tile[r][tc] = W[(size_t)(k0 + r) * C + n0 + tc];
    }
    __syncthreads();
    #pragma unroll
    for (int i = 0; i < 4; ++i) {
        int r = tr + i * 8;
        Wot[(size_t)p * C * C + (size_t)(n0 + r) * C + k0 + tc] = f2bf(tile[tc][r]);
    }
}

// ---------------------------------------------------------------- QKV proj MFMA
__global__ __launch_bounds__(256) void proj_mfma(
    const u16* __restrict__ Xb, const u16* __restrict__ Wt,
    const float* __restrict__ bq, const float* __restrict__ bk,
    const float* __restrict__ bv,
    u16* __restrict__ out)
{
    constexpr int BK = 64;
    int p = blockIdx.z;
    int e = p / 3, t = p % 3;
    const float* bias = (t == 0 ? bq : (t == 1 ? bk : bv)) + (size_t)e * C;
    u16* Y = out + (size_t)p * S;
    const u16* Wp = Wt + (size_t)p * C * C;

    int m0 = blockIdx.y * 128;
    int n0 = blockIdx.x * 128;

    __shared__ u16 As[128 * BK];
    __shared__ u16 Bs[128 * BK];

    int tid  = threadIdx.x;
    int lane = tid & 63;
    int wid  = tid >> 6;
    int wr = wid >> 1, wc = wid & 1;

    f32x4 acc[4][4];
    #pragma unroll
    for (int m = 0; m < 4; ++m)
        #pragma unroll
        for (int n = 0; n < 4; ++n)
            acc[m][n] = (f32x4){0.f, 0.f, 0.f, 0.f};

    int rowA = wr * 64 + (lane & 15);
    int rowB = wc * 64 + (lane & 15);
    int kgrp = 8 * (lane >> 4);

    for (int kt = 0; kt < C / BK; ++kt) {
        int k0 = kt * BK;
        #pragma unroll
        for (int j = 0; j < 4; ++j) {
            int chunk = (wid * 4 + j) * 64 + lane;
            int r = chunk >> 3;
            int k = (chunk & 7) << 3;
            gload16(Xb + (size_t)(m0 + r) * C + k0 + k, &As[(wid * 4 + j) * 512]);
            gload16(Wp + (size_t)(n0 + r) * C + k0 + k, &Bs[(wid * 4 + j) * 512]);
        }
        __syncthreads();
        #pragma unroll
        for (int ks = 0; ks < 2; ++ks) {
            int kb = ks * 32 + kgrp;
            short8 af[4], bfr[4];
            #pragma unroll
            for (int m = 0; m < 4; ++m)
                af[m] = *reinterpret_cast<const short8*>(&As[(rowA + m * 16) * BK + kb]);
            #pragma unroll
            for (int n = 0; n < 4; ++n)
                bfr[n] = *reinterpret_cast<const short8*>(&Bs[(rowB + n * 16) * BK + kb]);
            #pragma unroll
            for (int m = 0; m < 4; ++m)
                #pragma unroll
                for (int n = 0; n < 4; ++n)
                    acc[m][n] = __builtin_amdgcn_mfma_f32_16x16x32_bf16(
                        af[m], bfr[n], acc[m][n], 0, 0, 0);
        }
        __syncthreads();
    }

    int colb = n0 + wc * 64 + (lane & 15);
    int rowb = m0 + wr * 64 + (lane >> 4) * 4;
    #pragma unroll
    for (int n = 0; n < 4; ++n) {
        int col = colb + n * 16;
        float bcol = bias[col];
        #pragma unroll
        for (int m = 0; m < 4; ++m) {
            #pragma unroll
            for (int r = 0; r < 4; ++r) {
                int row = rowb + m * 16 + r;
                Y[(size_t)row * C + col] = f2bf(acc[m][n][r] + bcol);
            }
        }
    }
}

// ---------------------------------------------------------------- MFMA flash attention
// block = (head, slot, bh*2+qh); 4 waves; wave w owns q-columns
// [qh*128 + w*32, +32). Swapped orientation: S^T = K Q^T, O^T = V^T P^T.
__global__ __launch_bounds__(256) void attn_mfma(
    const u16* __restrict__ qkv,
    const int* __restrict__ indx, const int* __restrict__ expertArr,
    u16* __restrict__ Obuf)
{
    int head = blockIdx.x;
    int slot = blockIdx.y;
    int z    = blockIdx.z;
    int bh   = z >> 1, qh = z & 1;
    int b    = bh >> 3;
    int mi   = bh * KS + slot;
    int src  = indx[mi];
    int e    = expertArr[mi];
    int qbase = qh * 128;

    const u16* qp = qkv + (size_t)(e * 3 + 0) * S + (size_t)bh * L * C + head * DH;
    const u16* kp = qkv + (size_t)(e * 3 + 1) * S + (size_t)(b * H + src) * L * C + head * DH;
    const u16* vp = qkv + (size_t)(e * 3 + 2) * S + (size_t)(b * H + src) * L * C + head * DH;

    __shared__ u16 Ks[64 * 64];        // [kk][d] swizzled, 8KB
    __shared__ u16 Vt[64 * 64];        // [d][kk] swizzled, 8KB
    __shared__ u16 Pl[4][32 * 64];     // per-wave P[q][kk] swizzled, 16KB

    int tid = threadIdx.x, lane = tid & 63, w = tid >> 6;
    int c = lane & 15, gl = lane >> 4;
    int qoff = qbase + w * 32;

    // Q B-fragments: lane holds Q[q = qoff + n*16 + c][d = kf*32 + 8gl + j]
    short8 qf[2][2];
    #pragma unroll
    for (int n = 0; n < 2; ++n)
        #pragma unroll
        for (int kf = 0; kf < 2; ++kf)
            qf[n][kf] = *reinterpret_cast<const short8*>(
                qp + (size_t)(qoff + n * 16 + c) * C + kf * 32 + 8 * gl);

    f32x4 accO[4][2];   // O^T[d = m*16+4gl+r][q = n*16+c]
    #pragma unroll
    for (int m = 0; m < 4; ++m)
        #pragma unroll
        for (int n = 0; n < 2; ++n)
            accO[m][n] = (f32x4){0.f, 0.f, 0.f, 0.f};
    float mrun[2], lrun[2];
    #pragma unroll
    for (int n = 0; n < 2; ++n) { mrun[n] = -1e30f; lrun[n] = 0.f; }

    char* Plw = (char*)&Pl[w][0];

    for (int t = 0; t < 4; ++t) {
        int c0 = t * 64;
        __syncthreads();
        // --- stage K: [kk][d], XOR-swizzled rows (reg-staged)
        #pragma unroll
        for (int it = 0; it < 2; ++it) {
            int ch = tid + 256 * it;
            int r = ch >> 3, cb = ch & 7;
            short8 kv = *reinterpret_cast<const short8*>(kp + (size_t)(c0 + r) * C + cb * 8);
            int ad = (r * 128 + cb * 16) ^ ((r & 7) << 4);
            *reinterpret_cast<short8*>((char*)Ks + ad) = kv;
        }
        // --- stage V transposed: Vt[d][kk], pair-packed along kk
        {
            int rp = tid & 31;          // kk pair index
            int d0 = (tid >> 5) * 8;
            const u16* v0p = vp + (size_t)(c0 + 2 * rp) * C + d0;
            const u16* v1p = v0p + C;
            ushort4 a0 = *reinterpret_cast<const ushort4*>(v0p);
            ushort4 a1 = *reinterpret_cast<const ushort4*>(v0p + 4);
            ushort4 b0 = *reinterpret_cast<const ushort4*>(v1p);
            ushort4 b1 = *reinterpret_cast<const ushort4*>(v1p + 4);
            u16 va[8] = {a0.x, a0.y, a0.z, a0.w, a1.x, a1.y, a1.z, a1.w};
            u16 vb[8] = {b0.x, b0.y, b0.z, b0.w, b1.x, b1.y, b1.z, b1.w};
            #pragma unroll
            for (int j = 0; j < 8; ++j) {
                u32 pk = ((u32)vb[j] << 16) | (u32)va[j];
                int ad = ((d0 + j) * 128 + rp * 4) ^ (((d0 + j) & 7) << 4);
                *reinterpret_cast<u32*>((char*)Vt + ad) = pk;
            }
        }
        __syncthreads();

        // --- QK^T (swapped): accS = S^T tile [kk=64][q=32]
        f32x4 accS[4][2];
        #pragma unroll
        for (int m = 0; m < 4; ++m)
            #pragma unroll
            for (int n = 0; n < 2; ++n)
                accS[m][n] = (f32x4){0.f, 0.f, 0.f, 0.f};
        #pragma unroll
        for (int kf = 0; kf < 2; ++kf) {
            short8 ka[4];
            #pragma unroll
            for (int m = 0; m < 4; ++m) {
                int row = m * 16 + c;
                ka[m] = *reinterpret_cast<const short8*>(
                    (char*)Ks + ((row * 128 + (kf * 32 + 8 * gl) * 2) ^ ((row & 7) << 4)));
            }
            #pragma unroll
            for (int m = 0; m < 4; ++m)
                #pragma unroll
                for (int n = 0; n < 2; ++n)
                    accS[m][n] = __builtin_amdgcn_mfma_f32_16x16x32_bf16(
                        ka[m], qf[n][kf], accS[m][n], 0, 0, 0);
        }

        // --- online softmax per q-column (n); write P to wave-private LDS
        #pragma unroll
        for (int n = 0; n < 2; ++n) {
            float tm = -1e30f;
            #pragma unroll
            for (int m = 0; m < 4; ++m)
                #pragma unroll
                for (int r = 0; r < 4; ++r)
                    tm = fmaxf(tm, accS[m][n][r] * 0.125f);
            tm = fmaxf(tm, __shfl_xor(tm, 16));
            tm = fmaxf(tm, __shfl_xor(tm, 32));
            float nm = fmaxf(mrun[n], tm);
            float al = __expf(mrun[n] - nm);
            mrun[n] = nm;
            lrun[n] *= al;
            #pragma unroll
            for (int m = 0; m < 4; ++m)
                #pragma unroll
                for (int r = 0; r < 4; ++r)
                    accO[m][n][r] *= al;
            float ps = 0.f;
            #pragma unroll
            for (int m = 0; m < 4; ++m)
                #pragma unroll
                for (int r = 0; r < 4; ++r) {
                    float pv = __expf(accS[m][n][r] * 0.125f - nm);
                    accS[m][n][r] = pv;
                    ps += pv;
                }
            lrun[n] += ps;
            int row = n * 16 + c;
            int sw = (row & 7) << 4;
            #pragma unroll
            for (int m = 0; m < 4; ++m) {
                u32 p0 = packbf(accS[m][n][0], accS[m][n][1]);
                u32 p1 = packbf(accS[m][n][2], accS[m][n][3]);
                int base = row * 128 + (m * 16 + 4 * gl) * 2;
                *reinterpret_cast<u32*>(Plw + (base ^ sw)) = p0;
                *reinterpret_cast<u32*>(Plw + ((base + 4) ^ sw)) = p1;
            }
        }

        // --- PV (swapped): accO += V^T · P^T
        #pragma unroll
        for (int kf = 0; kf < 2; ++kf) {
            short8 va[4], pb[2];
            #pragma unroll
            for (int m = 0; m < 4; ++m) {
                int row = m * 16 + c;
                va[m] = *reinterpret_cast<const short8*>(
                    (char*)Vt + ((row * 128 + (kf * 32 + 8 * gl) * 2) ^ ((row & 7) << 4)));
            }
            #pragma unroll
            for (int n = 0; n < 2; ++n) {
                int row = n * 16 + c;
                pb[n] = *reinterpret_cast<const short8*>(
                    Plw + ((row * 128 + (kf * 32 + 8 * gl) * 2) ^ ((row & 7) << 4)));
            }
            #pragma unroll
            for (int m = 0; m < 4; ++m)
                #pragma unroll
                for (int n = 0; n < 2; ++n)
                    accO[m][n] = __builtin_amdgcn_mfma_f32_16x16x32_bf16(
                        va[m], pb[n], accO[m][n], 0, 0, 0);
        }
    }

    // --- epilogue: normalize, transpose via LDS, coalesced store
    float inv[2];
    #pragma unroll
    for (int n = 0; n < 2; ++n) {
        float lv = lrun[n];
        lv += __shfl_xor(lv, 16);
        lv += __shfl_xor(lv, 32);
        inv[n] = 1.f / lv;
    }
    #pragma unroll
    for (int m = 0; m < 4; ++m)
        #pragma unroll
        for (int n = 0; n < 2; ++n) {
            int row = n * 16 + c;          // q (0..31)
            int sw = (row & 7) << 4;
            float o0 = accO[m][n][0] * inv[n];
            float o1 = accO[m][n][1] * inv[n];
            float o2 = accO[m][n][2] * inv[n];
            float o3 = accO[m][n][3] * inv[n];
            int base = row * 128 + (m * 16 + 4 * gl) * 2;   // d = m*16+4gl
            *reinterpret_cast<u32*>(Plw + (base ^ sw)) = packbf(o0, o1);
            *reinterpret_cast<u32*>(Plw + ((base + 4) ^ sw)) = packbf(o2, o3);
        }
    #pragma unroll
    for (int it = 0; it < 4; ++it) {
        int q = it * 8 + (lane >> 3), cb = lane & 7;
        short8 ov = *reinterpret_cast<const short8*>(
            Plw + ((q * 128 + cb * 16) ^ ((q & 7) << 4)));
        *reinterpret_cast<short8*>(
            Obuf + ((size_t)mi * L + qoff + q) * C + head * DH + cb * 8) = ov;
    }
}

// ---------------------------------------------------------------- Wo + combine (MFMA)
__global__ __launch_bounds__(256) void wo_mfma(
    const u16* __restrict__ Obuf, const u16* __restrict__ Wot,
    const float* __restrict__ bo,
    const float* __restrict__ attnw, const int* __restrict__ expertArr,
    float* __restrict__ wise)
{
    constexpr int BK = 64;
    int bh = blockIdx.z;
    int m0 = blockIdx.y * 64;
    int n0 = blockIdx.x * 128;

    __shared__ u16 As[64 * BK];
    __shared__ u16 Bs[128 * BK];

    int tid = threadIdx.x, lane = tid & 63, wid = tid >> 6;
    int wr = wid >> 1, wc = wid & 1;
    int c = lane & 15, gl = lane >> 4;

    f32x4 acc[2][4];
    #pragma unroll
    for (int m = 0; m < 2; ++m)
        #pragma unroll
        for (int n = 0; n < 4; ++n)
            acc[m][n] = (f32x4){0.f, 0.f, 0.f, 0.f};

    for (int k = 0; k < KS; ++k) {
        int mi = bh * KS + k;
        float ak = attnw[mi];
        int e = expertArr[mi];
        const u16* Ap = Obuf + (size_t)mi * L * C + (size_t)m0 * C;
        const u16* Bp = Wot + (size_t)e * C * C + (size_t)n0 * C;
        for (int kt = 0; kt < C / BK; ++kt) {
            int k0 = kt * BK;
            __syncthreads();
            #pragma unroll
            for (int it = 0; it < 2; ++it) {
                int ch = tid + 256 * it;
                int r = ch >> 3, cb = ch & 7;
                short8 a8 = *reinterpret_cast<const short8*>(Ap + (size_t)r * C + k0 + cb * 8);
                short8 o8;
                #pragma unroll
                for (int j = 0; j < 8; ++j)
                    o8[j] = (short)f2bf(bf2f((u16)a8[j]) * ak);
                *reinterpret_cast<short8*>(&As[r * BK + cb * 8]) = o8;
            }
            #pragma unroll
            for (int j = 0; j < 4; ++j) {
                int chunk = (wid * 4 + j) * 64 + lane;
                int r = chunk >> 3;
                int kk = (chunk & 7) << 3;
                gload16(Bp + (size_t)r * C + k0 + kk, &Bs[(wid * 4 + j) * 512]);
            }
            __syncthreads();
            #pragma unroll
            for (int ks = 0; ks < 2; ++ks) {
                int kb = ks * 32 + 8 * gl;
                short8 af[2], bfr[4];
                #pragma unroll
                for (int m = 0; m < 2; ++m)
                    af[m] = *reinterpret_cast<const short8*>(&As[(wr * 32 + m * 16 + c) * BK + kb]);
                #pragma unroll
                for (int n = 0; n < 4; ++n)
                    bfr[n] = *reinterpret_cast<const short8*>(&Bs[(wc * 64 + n * 16 + c) * BK + kb]);
                #pragma unroll
                for (int m = 0; m < 2; ++m)
                    #pragma unroll
                    for (int n = 0; n < 4; ++n)
                        acc[m][n] = __builtin_amdgcn_mfma_f32_16x16x32_bf16(
                            af[m], bfr[n], acc[m][n], 0, 0, 0);
            }
        }
    }

    float biasS[4] = {0.f, 0.f, 0.f, 0.f};
    #pragma unroll
    for (int k = 0; k < KS; ++k) {
        int mi = bh * KS + k;
        float ak = attnw[mi];
        int e = expertArr[mi];
        #pragma unroll
        for (int n = 0; n < 4; ++n)
            biasS[n] += ak * bo[(size_t)e * C + n0 + wc * 64 + n * 16 + c];
    }
    #pragma unroll
    for (int m = 0; m < 2; ++m) {
        #pragma unroll
        for (int r = 0; r < 4; ++r) {
            int row = m0 + wr * 32 + m * 16 + 4 * gl + r;
            #pragma unroll
            for (int n = 0; n < 4; ++n) {
                int col = n0 + wc * 64 + n * 16 + c;
                wise[(size_t)bh * L * C + (size_t)row * C + col] = acc[m][n][r] + biasS[n];
            }
        }
    }
}

// ---------------------------------------------------------------- relu + add (+bf16 cast)
__global__ __launch_bounds__(256) void ew_relu_add_cast(
    const float* __restrict__ wise, const float* __restrict__ xin,
    float* __restrict__ xout, u16* __restrict__ Xb)
{
    size_t i4 = (size_t)blockIdx.x * 256 + threadIdx.x;
    size_t elem = i4 * 4;
    float4 w = *reinterpret_cast<const float4*>(wise + elem);
    float4 x = *reinterpret_cast<const float4*>(xin + elem);
    float4 o;
    o.x = fmaxf(w.x, 0.f) + x.x;
    o.y = fmaxf(w.y, 0.f) + x.y;
    o.z = fmaxf(w.z, 0.f) + x.z;
    o.w = fmaxf(w.w, 0.f) + x.w;
    *reinterpret_cast<float4*>(xout + elem) = o;
    ushort4 ob;
    ob.x = f2bf(o.x); ob.y = f2bf(o.y); ob.z = f2bf(o.z); ob.w = f2bf(o.w);
    *reinterpret_cast<ushort4*>(Xb + elem) = ob;
}

// ----------------------------------------------------------------------------
extern "C" void kernel_launch(void* const* d_in, const int* in_sizes, int n_in,
                              void* d_out, int out_size, void* d_ws, size_t ws_size,
                              hipStream_t stream) {
    const float* gmap = (const float*)d_in[0];
    const float* hist = (const float*)d_in[1];
    const float* cur  = (const float*)d_in[2];
    const float* Wq   = (const float*)d_in[6];
    const float* bq   = (const float*)d_in[7];
    const float* Wk   = (const float*)d_in[8];
    const float* bk   = (const float*)d_in[9];
    const float* Wv   = (const float*)d_in[10];
    const float* bv   = (const float*)d_in[11];
    const float* Wo   = (const float*)d_in[12];
    const float* bo   = (const float*)d_in[13];
    float* outp       = (float*)d_out;

    char* ws = (char*)d_ws;
    float* ctx  = (float*)(ws);                      // [0,4S)
    float* x1   = (float*)(ws + 4 * S);              // [4S,8S)
    float* wise = (float*)(ws + 8 * S);              // [8S,12S)
    u16*   qkv  = (u16*)(ws + 12 * S);               // [12S,30S)
    u16*   Obuf = (u16*)(ws + 30 * S);               // [30S,38S)
    char*  tail = ws + 38 * S;
    float* attnw  = (float*)(tail);                  // 256 B
    int*   indx   = (int*)(tail + 256);
    int*   expert = (int*)(tail + 512);
    u16*   Wot    = (u16*)(tail + 4096);             // 3*C*C*2 = 1.57 MB
    u16*   Xb     = (u16*)(tail + 4096 + 2 * 1024 * 1024);   // 2S bytes = 4 MB
    u16*   Wt     = (u16*)(tail + 4096 + 8 * 1024 * 1024);   // 9*C*C*2 = 4.7 MB

    dim3 projGrid(C / 128, M4 / 128, 9);
    dim3 castWGrid(C / 32, C / 32, 9);
    dim3 castWoGrid(C / 32, C / 32, 3);
    dim3 attnGrid(NH, KS, BH * 2);
    dim3 woGrid(C / 128, L / 64, BH);
    int ewBlocks = (int)(S / 4 / 256);   // 2048

    concat_cast_kernel<<<ewBlocks, 256, 0, stream>>>(hist, cur, ctx, Xb);
    topk_kernel<<<1, 64, 0, stream>>>(gmap, attnw, indx, expert);
    cast_wo_kernel<<<castWoGrid, 256, 0, stream>>>(Wo, Wot);
    cast_w_kernel<<<castWGrid, 256, 0, stream>>>(Wq, Wk, Wv, Wt);   // once for both layers

    // ---- layer 1: ctx -> x1
    proj_mfma<<<projGrid, 256, 0, stream>>>(Xb, Wt, bq, bk, bv, qkv);
    attn_mfma<<<attnGrid, 256, 0, stream>>>(qkv, indx, expert, Obuf);
    wo_mfma<<<woGrid, 256, 0, stream>>>(Obuf, Wot, bo, attnw, expert, wise);
    ew_relu_add_cast<<<ewBlocks, 256, 0, stream>>>(wise, ctx, x1, Xb);

    // ---- layer 2: x1 -> out
    proj_mfma<<<projGrid, 256, 0, stream>>>(Xb, Wt, bq, bk, bv, qkv);
    attn_mfma<<<attnGrid, 256, 0, stream>>>(qkv, indx, expert, Obuf);
    wo_mfma<<<woGrid, 256, 0, stream>>>(Obuf, Wot, bo, attnw, expert, wise);
    ew_relu_add_cast<<<ewBlocks, 256, 0, stream>>>(wise, x1, outp, Xb);
}